// Round 18
// baseline (398.518 us; speedup 1.0000x reference)
//
#include <hip/hip_runtime.h>
#include <math.h>

// MambaForecaster: B=16, L=2048, Dm=64, NL=4, ED=128, N=16, R=4, DC=4
#define B_   16
#define L_   2048
#define DM   64
#define NL_  4
#define ED_  128
#define NS   16
#define RK   4
#define BL   (B_*L_)          // 32768 rows
#define CHUNKS 128
#define CHLEN  (L_/CHUNKS)    // 16
#define SEQS   (B_*ED_*NS)    // 32768 sequences for the combine
#define BE    (B_*ED_)        // 2048 (b,e) pairs

// Build r^{1..16} from r with 15 muls (depth 4). p[n] = r^{n+1}.
__device__ __forceinline__ void pow_chain16(float r, float* p) {
  float r2 = r * r, r4 = r2 * r2, r8 = r4 * r4;
  p[0]=r;      p[1]=r2;      p[2]=r2*r;    p[3]=r4;
  p[4]=r4*r;   p[5]=r4*r2;   p[6]=r4*p[2]; p[7]=r8;
  p[8]=r8*r;   p[9]=r8*r2;   p[10]=r8*p[2];p[11]=r8*r4;
  p[12]=r8*p[4];p[13]=r8*p[5];p[14]=r8*p[6];p[15]=r8*r8;
}

// ---- GEMM1 + fused RMSNorm: xz = rmsnorm(x) @ in_w^T  (M=BL,K=64,N=256) ----
__global__ __launch_bounds__(256) void gemm_in_rms_k(const float* __restrict__ X,
    const float* __restrict__ nw, const float* __restrict__ W, float* __restrict__ XZ)
{
  __shared__ float4 sX[64][17];    // 64 rows x 64 K, padded (17.4 KB)
  __shared__ float4 sW[16][64];    // [k4][c], 64 cols       (16 KB)
  int tid = threadIdx.x;
  int row0 = blockIdx.x * 64;
  int col0 = blockIdx.y * 64;
  const float* Wh = W + (size_t)col0 * 64;
#pragma unroll
  for (int it = 0; it < 4; it++) {
    int i = tid + it * 256;
    int r = i >> 4, q = i & 15;
    float4 v = *(const float4*)(X + (size_t)(row0 + r) * 64 + q * 4);
    float ss = v.x*v.x + v.y*v.y + v.z*v.z + v.w*v.w;
    ss += __shfl_xor(ss, 1, 16);
    ss += __shfl_xor(ss, 2, 16);
    ss += __shfl_xor(ss, 4, 16);
    ss += __shfl_xor(ss, 8, 16);
    float sc = rsqrtf(ss * (1.0f/64.0f) + 1e-5f);
    float4 wv = *(const float4*)(nw + q * 4);
    float4 o;
    o.x = v.x*sc*wv.x; o.y = v.y*sc*wv.y; o.z = v.z*sc*wv.z; o.w = v.w*sc*wv.w;
    sX[r][q] = o;
  }
#pragma unroll
  for (int it = 0; it < 4; it++) {
    int i = tid + it * 256;
    int c = i >> 4, k4 = i & 15;
    sW[k4][c] = *(const float4*)(Wh + (size_t)c * 64 + k4 * 4);
  }
  __syncthreads();
  int rg = tid >> 4;   // rows 4rg..4rg+3
  int cg = tid & 15;   // cols cg + 16j, j<4
  float acc[4][4];
#pragma unroll
  for (int i = 0; i < 4; i++)
#pragma unroll
    for (int j = 0; j < 4; j++) acc[i][j] = 0.f;
  for (int k4 = 0; k4 < 16; k4++) {
    float4 x[4];
#pragma unroll
    for (int i = 0; i < 4; i++) x[i] = sX[4*rg + i][k4];
#pragma unroll
    for (int j = 0; j < 4; j++) {
      float4 wv = sW[k4][cg + 16*j];
#pragma unroll
      for (int i = 0; i < 4; i++) {
        acc[i][j] = fmaf(x[i].x,wv.x, fmaf(x[i].y,wv.y,
                    fmaf(x[i].z,wv.z, fmaf(x[i].w,wv.w, acc[i][j]))));
      }
    }
  }
#pragma unroll
  for (int i = 0; i < 4; i++) {
#pragma unroll
    for (int j = 0; j < 4; j++) {
      XZ[(size_t)(row0 + 4*rg + i) * 256 + col0 + cg + 16*j] = acc[i][j];
    }
  }
}

// ---- fused conv+silu+GEMM2+scan-pass1: 64 rows (4 chunks), 512 threads ----
// Writes h-summaries (HZ) and per-chunk delta-sum (SS); ap is reconstructed
// in the combine as exp(a*Ssum) -- saves the 16-wide AP array round trip.
__global__ __launch_bounds__(512) void convdbc_scan1_k(const float* __restrict__ XZ,
    const float* __restrict__ cw, const float* __restrict__ cb,
    const float* __restrict__ W,
    const float* __restrict__ dtw, const float* __restrict__ dtb,
    const float* __restrict__ alog,
    float* __restrict__ XI, float* __restrict__ DBC,
    float* __restrict__ SS, float* __restrict__ HZ)
{
  __shared__ float4 sX[64][33];               // conv+silu out, padded (33.8 KB)
  __shared__ float4 sW[32][40];               // [k4][f] padded 36->40 (20 KB)
  __shared__ __align__(16) float sDBC[64*40]; // [row][36 pad 40]      (10.2 KB)
  int tid = threadIdx.x;
  int row0 = blockIdx.x * 64;
  int l0 = row0 & (L_ - 1);
  int b  = row0 >> 11;                        // /2048
  // phase 1: conv+silu staging
#pragma unroll
  for (int it = 0; it < 4; it++) {
    int i = tid + it * 512;
    int r = i >> 5, k4 = i & 31;
    int l = l0 + r;
    const float* base = XZ + (size_t)(row0 + r) * 256 + k4 * 4;
    float4 z4 = make_float4(0.f,0.f,0.f,0.f);
    float4 t3 = (l >= 3) ? *(const float4*)(base - 3*256) : z4;
    float4 t2 = (l >= 2) ? *(const float4*)(base - 2*256) : z4;
    float4 t1 = (l >= 1) ? *(const float4*)(base - 1*256) : z4;
    float4 t0 = *(const float4*)(base);
    float4 w0 = *(const float4*)(cw + (k4*4+0)*4);
    float4 w1 = *(const float4*)(cw + (k4*4+1)*4);
    float4 w2 = *(const float4*)(cw + (k4*4+2)*4);
    float4 w3 = *(const float4*)(cw + (k4*4+3)*4);
    float4 bb = *(const float4*)(cb + k4*4);
    float4 o;
    o.x = fmaf(t3.x,w0.x, fmaf(t2.x,w0.y, fmaf(t1.x,w0.z, fmaf(t0.x,w0.w, bb.x))));
    o.y = fmaf(t3.y,w1.x, fmaf(t2.y,w1.y, fmaf(t1.y,w1.z, fmaf(t0.y,w1.w, bb.y))));
    o.z = fmaf(t3.z,w2.x, fmaf(t2.z,w2.y, fmaf(t1.z,w2.z, fmaf(t0.z,w2.w, bb.z))));
    o.w = fmaf(t3.w,w3.x, fmaf(t2.w,w3.y, fmaf(t1.w,w3.z, fmaf(t0.w,w3.w, bb.w))));
    o.x = o.x / (1.f + __expf(-o.x));
    o.y = o.y / (1.f + __expf(-o.y));
    o.z = o.z / (1.f + __expf(-o.z));
    o.w = o.w / (1.f + __expf(-o.w));
    sX[r][k4] = o;
    *(float4*)(XI + (size_t)(row0 + r) * 128 + k4 * 4) = o;
  }
  for (int i = tid; i < 36 * 32; i += 512) {
    int f = i >> 5, k4 = i & 31;
    sW[k4][f] = *(const float4*)(W + (size_t)f * 128 + k4 * 4);
  }
  __syncthreads();
  // phase 2: dbc = xi @ xpw^T. 1 row/thread (r=tid>>3 in 0..63), 5 cols
  {
    int r  = tid >> 3;
    int cg = tid & 7;
    float acc[5];
#pragma unroll
    for (int j = 0; j < 5; j++) acc[j] = 0.f;
    for (int k4 = 0; k4 < 32; k4++) {
      float4 x0 = sX[r][k4];
#pragma unroll
      for (int j = 0; j < 5; j++) {
        float4 wv = sW[k4][cg + 8*j];
        acc[j] = fmaf(x0.x,wv.x, fmaf(x0.y,wv.y, fmaf(x0.z,wv.z, fmaf(x0.w,wv.w, acc[j]))));
      }
    }
#pragma unroll
    for (int j = 0; j < 5; j++) {
      int c = cg + 8*j;
      if (c < 36) {
        DBC[(size_t)(row0 + r) * 36 + c] = acc[j];
        sDBC[r*40 + c] = acc[j];
      }
    }
  }
  __syncthreads();
  // phase 3: chunk-scan summaries. 128 e-lanes x 4 quarters.
  {
    int e = tid & 127;
    int q = tid >> 7;                           // 0..3
    float a[NS];
#pragma unroll
    for (int n = 0; n < NS; n++) a[n] = -__expf(alog[e*NS + n]);
    bool fast = true;
#pragma unroll
    for (int n = 0; n < NS; n++) fast = fast && (fabsf(a[n] + (float)(n+1)) <= 1e-3f);
    float4 w4 = *(const float4*)(dtw + e*4);
    float bias = dtb[e];
    const float* sXf = (const float*)sX;
    float h[NS];
#pragma unroll
    for (int n = 0; n < NS; n++) h[n] = 0.f;
    float Ssum = 0.f;
    for (int t = 0; t < CHLEN; t++) {
      int r = q * CHLEN + t;
      const float* dr = sDBC + r * 40;
      float4 d4 = *(const float4*)dr;
      float pre = fmaf(d4.x,w4.x, fmaf(d4.y,w4.y, fmaf(d4.z,w4.z, fmaf(d4.w,w4.w, bias))));
      float ex = __expf(pre);
      float delta = (pre > 20.f) ? pre : __logf(1.f + ex);   // softplus
      Ssum += delta;
      float xi = sXf[r * 132 + e];
      float dx = delta * xi;
      float4 b0 = *(const float4*)(dr + 4);
      float4 b1 = *(const float4*)(dr + 8);
      float4 b2 = *(const float4*)(dr + 12);
      float4 b3 = *(const float4*)(dr + 16);
      float Bv[NS] = {b0.x,b0.y,b0.z,b0.w, b1.x,b1.y,b1.z,b1.w,
                      b2.x,b2.y,b2.z,b2.w, b3.x,b3.y,b3.z,b3.w};
      float p[NS];
      if (fast) {
        pow_chain16(__expf(-delta), p);
      } else {
#pragma unroll
        for (int n = 0; n < NS; n++) p[n] = __expf(delta * a[n]);
      }
#pragma unroll
      for (int n = 0; n < NS; n++) h[n] = fmaf(p[n], h[n], dx * Bv[n]);
    }
    int ch = (l0 >> 4) + q;
    SS[(size_t)ch * BE + b * ED_ + e] = Ssum;
    size_t base = (size_t)ch * SEQS + ((size_t)(b * ED_ + e)) * NS;
#pragma unroll
    for (int i = 0; i < 4; i++) {
      *(float4*)(HZ + base + i*4) = make_float4(h[4*i], h[4*i+1], h[4*i+2], h[4*i+3]);
    }
  }
}

// ---- scan combine: 64 sequences/block; ap reconstructed from SS + alog ----
__global__ __launch_bounds__(256) void scan_combine_k(const float* __restrict__ SS,
    const float* __restrict__ HZ, const float* __restrict__ alog,
    float* __restrict__ HI)
{
  __shared__ float sA[CHUNKS * 65];   // 33.3 KB
  __shared__ float sH[CHUNKS * 65];   // 33.3 KB
  __shared__ float aLoc[64];
  int tid = threadIdx.x;
  int t0 = blockIdx.x * 64;
  if (tid < 64) {
    int gt = t0 + tid;
    aLoc[tid] = -__expf(alog[(((gt >> 4) & (ED_ - 1)) * NS) + (gt & 15)]);
  }
  __syncthreads();
  for (int i = tid; i < CHUNKS * 64; i += 256) {
    int ch = i >> 6, s = i & 63;
    int be = (t0 + s) >> 4;
    sA[ch*65 + s] = __expf(aLoc[s] * SS[(size_t)ch * BE + be]);
    sH[ch*65 + s] = HZ[(size_t)ch * SEQS + t0 + s];
  }
  __syncthreads();
  int lane = tid & 63;
  int wid = tid >> 6;          // 4 waves, 16 sequences each
  for (int j = 0; j < 16; j++) {
    int s = wid * 16 + j;
    float a0 = sA[(2*lane)*65 + s],   h0 = sH[(2*lane)*65 + s];
    float a1 = sA[(2*lane+1)*65 + s], h1 = sH[(2*lane+1)*65 + s];
    float aL = a0 * a1;
    float hL = fmaf(a1, h0, h1);
#pragma unroll
    for (int off = 1; off < 64; off <<= 1) {
      float aP = __shfl_up(aL, off, 64);
      float hP = __shfl_up(hL, off, 64);
      if (lane >= off) { hL = fmaf(aL, hP, hL); aL = aP * aL; }
    }
    float hPrev = __shfl_up(hL, 1, 64);
    if (lane == 0) hPrev = 0.f;
    sA[(2*lane)*65 + s]   = hPrev;
    sA[(2*lane+1)*65 + s] = fmaf(a0, hPrev, h0);
  }
  __syncthreads();
  for (int i = tid; i < CHUNKS * 64; i += 256) {
    int ch = i >> 6, s = i & 63;
    HI[(size_t)ch * SEQS + t0 + s] = sA[ch*65 + s];
  }
}

// ---- pass2 + gating + out-proj + residual. 512 thr, 4 chunks (64 rows)/block ----
__global__ __launch_bounds__(512) void pass2_out_k(
    const float* __restrict__ DBC_, const float* __restrict__ XI_,
    const float* __restrict__ XZ,
    const float* __restrict__ dtw, const float* __restrict__ dtb,
    const float* __restrict__ alog, const float* __restrict__ Dp_,
    const float* __restrict__ HI,
    const float* __restrict__ Wo, const float* __restrict__ XOLD,
    float* __restrict__ XNEW)
{
  __shared__ __align__(16) float sYX[64 * 132];  // staged XI -> gated y (33.8 KB)
  __shared__ float4 sWo[64][33];                 // [o][k4] padded      (33.8 KB)
  __shared__ __align__(16) float sDBC[64*40];    // [row][36 pad 40]    (10.2 KB)
  int tid = threadIdx.x;
  int row0 = blockIdx.x * 64;                    // 64 rows, within one batch
  int b   = row0 >> 11;
  int ch0 = (row0 & (L_ - 1)) >> 4;              // first of 4 chunks
#pragma unroll
  for (int it = 0; it < 4; it++) {
    int i = tid + it * 512;
    int o = i >> 5, k4 = i & 31;
    sWo[o][k4] = *(const float4*)(Wo + (size_t)o * 128 + k4 * 4);
  }
#pragma unroll
  for (int it = 0; it < 16; it++) {
    int i = tid + it * 512;
    int r = i >> 7, e = i & 127;
    sYX[r * 132 + e] = XI_[(size_t)row0 * 128 + i];
  }
  for (int i = tid; i < 64 * 36; i += 512) {
    sDBC[(i / 36) * 40 + (i % 36)] = DBC_[(size_t)row0 * 36 + i];
  }
  // register-stage the z-gate column for this thread's chunk (16 values)
  int e_  = tid & 127;
  int q_  = tid >> 7;
  float zreg[CHLEN];
  {
    int bl0 = b * L_ + (ch0 + q_) * CHLEN;
#pragma unroll
    for (int t = 0; t < CHLEN; t++)
      zreg[t] = XZ[(size_t)(bl0 + t) * 256 + 128 + e_];
  }
  __syncthreads();
  // scan phase: 128 e-lanes x 4 chunk-quarters
  {
    int e  = e_;
    int q  = q_;
    int ch = ch0 + q;
    float a[NS];
#pragma unroll
    for (int n = 0; n < NS; n++) a[n] = -__expf(alog[e*NS + n]);
    bool fast = true;
#pragma unroll
    for (int n = 0; n < NS; n++) fast = fast && (fabsf(a[n] + (float)(n+1)) <= 1e-3f);
    float4 w4 = *(const float4*)(dtw + e*4);
    float bias = dtb[e];
    float Dp = Dp_[e];
    size_t sbase = (size_t)ch * SEQS + ((size_t)(b * ED_ + e)) * NS;
    float h[NS];
#pragma unroll
    for (int i = 0; i < 4; i++) {
      float4 v = *(const float4*)(HI + sbase + i*4);
      h[4*i] = v.x; h[4*i+1] = v.y; h[4*i+2] = v.z; h[4*i+3] = v.w;
    }
#pragma unroll
    for (int t = 0; t < CHLEN; t++) {
      int r = q * CHLEN + t;
      const float* dr = sDBC + r * 40;
      float4 d4 = *(const float4*)dr;
      float pre = fmaf(d4.x,w4.x, fmaf(d4.y,w4.y, fmaf(d4.z,w4.z, fmaf(d4.w,w4.w, bias))));
      float ex = __expf(pre);
      float delta = (pre > 20.f) ? pre : __logf(1.f + ex);
      float xi = sYX[r * 132 + e];
      float dx = delta * xi;
      float4 b0 = *(const float4*)(dr + 4);
      float4 b1 = *(const float4*)(dr + 8);
      float4 b2 = *(const float4*)(dr + 12);
      float4 b3 = *(const float4*)(dr + 16);
      float4 c0 = *(const float4*)(dr + 20);
      float4 c1 = *(const float4*)(dr + 24);
      float4 c2 = *(const float4*)(dr + 28);
      float4 c3 = *(const float4*)(dr + 32);
      float Bv[NS] = {b0.x,b0.y,b0.z,b0.w, b1.x,b1.y,b1.z,b1.w,
                      b2.x,b2.y,b2.z,b2.w, b3.x,b3.y,b3.z,b3.w};
      float Cv[NS] = {c0.x,c0.y,c0.z,c0.w, c1.x,c1.y,c1.z,c1.w,
                      c2.x,c2.y,c2.z,c2.w, c3.x,c3.y,c3.z,c3.w};
      float p[NS];
      if (fast) {
        pow_chain16(__expf(-delta), p);
      } else {
#pragma unroll
        for (int n = 0; n < NS; n++) p[n] = __expf(delta * a[n]);
      }
      float y = 0.f;
#pragma unroll
      for (int n = 0; n < NS; n++) {
        h[n] = fmaf(p[n], h[n], dx * Bv[n]);
        y = fmaf(h[n], Cv[n], y);
      }
      y = fmaf(Dp, xi, y);
      float z = zreg[t];
      float sz = z / (1.f + __expf(-z));
      sYX[r * 132 + e] = y * sz;      // overwrite xi slot with gated y
    }
  }
  __syncthreads();
  // out-proj from LDS: 2 rows x 4 cols per thread across 512 threads
  {
    int r2 = tid >> 4;                 // 0..31 -> rows 2r2, 2r2+1
    int og = tid & 15;                 // cols og + 16j, j<4
    const float4* sY0 = (const float4*)(sYX + (2*r2    ) * 132);
    const float4* sY1 = (const float4*)(sYX + (2*r2 + 1) * 132);
    float acc0[4], acc1[4];
#pragma unroll
    for (int j = 0; j < 4; j++) { acc0[j] = 0.f; acc1[j] = 0.f; }
    for (int k4 = 0; k4 < 32; k4++) {
      float4 y0 = sY0[k4];
      float4 y1 = sY1[k4];
#pragma unroll
      for (int j = 0; j < 4; j++) {
        float4 wv = sWo[og + 16*j][k4];
        acc0[j] = fmaf(y0.x,wv.x, fmaf(y0.y,wv.y, fmaf(y0.z,wv.z, fmaf(y0.w,wv.w, acc0[j]))));
        acc1[j] = fmaf(y1.x,wv.x, fmaf(y1.y,wv.y, fmaf(y1.z,wv.z, fmaf(y1.w,wv.w, acc1[j]))));
      }
    }
#pragma unroll
    for (int j = 0; j < 4; j++) {
      int o = og + 16*j;
      size_t i0 = (size_t)(row0 + 2*r2    ) * 64 + o;
      size_t i1 = (size_t)(row0 + 2*r2 + 1) * 64 + o;
      XNEW[i0] = XOLD[i0] + acc0[j];
      XNEW[i1] = XOLD[i1] + acc1[j];
    }
  }
}

// ---- final head ----
__global__ __launch_bounds__(256) void final_k(const float* __restrict__ X,
    const float* __restrict__ fcw, const float* __restrict__ fcb, float* __restrict__ out)
{
  int t = blockIdx.x * 256 + threadIdx.x;   // 1024
  int b = t >> 6, o = t & 63;
  const float* xrow = X + ((size_t)b * L_ + (L_ - 1)) * 64;
  const float* wrow = fcw + o * 64;
  float acc = fcb[o];
#pragma unroll
  for (int d = 0; d < 64; d++) acc = fmaf(xrow[d], wrow[d], acc);
  out[t] = acc;
}

extern "C" void kernel_launch(void* const* d_in, const int* in_sizes, int n_in,
                              void* d_out, int out_size, void* d_ws, size_t ws_size,
                              hipStream_t stream)
{
  const float* x_in   = (const float*)d_in[0];
  const float* norm_w = (const float*)d_in[1];
  const float* in_w   = (const float*)d_in[2];
  const float* conv_w = (const float*)d_in[3];
  const float* conv_b = (const float*)d_in[4];
  const float* xp_w   = (const float*)d_in[5];
  const float* dt_w   = (const float*)d_in[6];
  const float* dt_b   = (const float*)d_in[7];
  const float* A_log  = (const float*)d_in[8];
  const float* D_skip = (const float*)d_in[9];
  const float* out_w  = (const float*)d_in[10];
  const float* fc_w   = (const float*)d_in[11];
  const float* fc_b   = (const float*)d_in[12];
  float* out = (float*)d_out;

  float* ws  = (float*)d_ws;
  float* X   = ws;                                  // BL*64
  float* XZ  = X   + (size_t)BL*64;                 // BL*256
  float* XI  = XZ  + (size_t)BL*256;                // BL*128
  float* DBC = XI  + (size_t)BL*128;                // BL*36
  float* SS  = DBC + (size_t)BL*36;                 // CHUNKS*BE (1M floats)
  float* HZ  = SS  + (size_t)CHUNKS*BE;             // CHUNKS*SEQS
  float* HI  = HZ  + (size_t)CHUNKS*SEQS;

  for (int l = 0; l < NL_; l++) {
    const float* xsrc = (l == 0) ? x_in : X;
    gemm_in_rms_k<<<dim3(BL/64, 4), 256, 0, stream>>>(xsrc, norm_w + l*DM,
                    in_w + (size_t)l*2*ED_*DM, XZ);
    convdbc_scan1_k<<<BL/64, 512, 0, stream>>>(XZ, conv_w + l*ED_*4, conv_b + l*ED_,
                    xp_w + (size_t)l*36*ED_,
                    dt_w + l*ED_*RK, dt_b + l*ED_, A_log + l*ED_*NS,
                    XI, DBC, SS, HZ);
    scan_combine_k<<<SEQS/64, 256, 0, stream>>>(SS, HZ, A_log + l*ED_*NS, HI);
    pass2_out_k<<<BL/64, 512, 0, stream>>>(DBC, XI, XZ,
                    dt_w + l*ED_*RK, dt_b + l*ED_, A_log + l*ED_*NS, D_skip + l*ED_,
                    HI, out_w + (size_t)l*DM*ED_, xsrc, X);
  }
  final_k<<<4, 256, 0, stream>>>(X, fc_w, fc_b, out);
}

// Round 19
// 393.058 us; speedup vs baseline: 1.0139x; 1.0139x over previous
//
#include <hip/hip_runtime.h>
#include <math.h>

// MambaForecaster: B=16, L=2048, Dm=64, NL=4, ED=128, N=16, R=4, DC=4
#define B_   16
#define L_   2048
#define DM   64
#define NL_  4
#define ED_  128
#define NS   16
#define RK   4
#define BL   (B_*L_)          // 32768 rows
#define CHUNKS 128
#define CHLEN  (L_/CHUNKS)    // 16
#define SEQS   (B_*ED_*NS)    // 32768 sequences for the combine

// Build r^{1..16} from r with 15 muls (depth 4). p[n] = r^{n+1}.
__device__ __forceinline__ void pow_chain16(float r, float* p) {
  float r2 = r * r, r4 = r2 * r2, r8 = r4 * r4;
  p[0]=r;      p[1]=r2;      p[2]=r2*r;    p[3]=r4;
  p[4]=r4*r;   p[5]=r4*r2;   p[6]=r4*p[2]; p[7]=r8;
  p[8]=r8*r;   p[9]=r8*r2;   p[10]=r8*p[2];p[11]=r8*r4;
  p[12]=r8*p[4];p[13]=r8*p[5];p[14]=r8*p[6];p[15]=r8*r8;
}

// ---- GEMM1 + fused RMSNorm: xz = rmsnorm(x) @ in_w^T  (M=BL,K=64,N=256) ----
// 64x64 tile, 4x4 register blocking: 8 LDS reads per 16 dots -> VALU-bound.
__global__ __launch_bounds__(256) void gemm_in_rms_k(const float* __restrict__ X,
    const float* __restrict__ nw, const float* __restrict__ W, float* __restrict__ XZ)
{
  __shared__ float4 sX[64][17];    // 64 rows x 64 K, padded (17.4 KB)
  __shared__ float4 sW[16][64];    // [k4][c], 64 cols       (16 KB)
  int tid = threadIdx.x;
  int row0 = blockIdx.x * 64;
  int col0 = blockIdx.y * 64;
  const float* Wh = W + (size_t)col0 * 64;
  // stage X with on-the-fly rmsnorm: 16 consecutive lanes own one row
#pragma unroll
  for (int it = 0; it < 4; it++) {
    int i = tid + it * 256;
    int r = i >> 4, q = i & 15;
    float4 v = *(const float4*)(X + (size_t)(row0 + r) * 64 + q * 4);
    float ss = v.x*v.x + v.y*v.y + v.z*v.z + v.w*v.w;
    ss += __shfl_xor(ss, 1, 16);
    ss += __shfl_xor(ss, 2, 16);
    ss += __shfl_xor(ss, 4, 16);
    ss += __shfl_xor(ss, 8, 16);
    float sc = rsqrtf(ss * (1.0f/64.0f) + 1e-5f);
    float4 wv = *(const float4*)(nw + q * 4);
    float4 o;
    o.x = v.x*sc*wv.x; o.y = v.y*sc*wv.y; o.z = v.z*sc*wv.z; o.w = v.w*sc*wv.w;
    sX[r][q] = o;
  }
#pragma unroll
  for (int it = 0; it < 4; it++) {
    int i = tid + it * 256;
    int c = i >> 4, k4 = i & 15;
    sW[k4][c] = *(const float4*)(Wh + (size_t)c * 64 + k4 * 4);
  }
  __syncthreads();
  int rg = tid >> 4;   // rows 4rg..4rg+3
  int cg = tid & 15;   // cols cg + 16j, j<4
  float acc[4][4];
#pragma unroll
  for (int i = 0; i < 4; i++)
#pragma unroll
    for (int j = 0; j < 4; j++) acc[i][j] = 0.f;
  for (int k4 = 0; k4 < 16; k4++) {
    float4 x[4];
#pragma unroll
    for (int i = 0; i < 4; i++) x[i] = sX[4*rg + i][k4];
#pragma unroll
    for (int j = 0; j < 4; j++) {
      float4 wv = sW[k4][cg + 16*j];
#pragma unroll
      for (int i = 0; i < 4; i++) {
        acc[i][j] = fmaf(x[i].x,wv.x, fmaf(x[i].y,wv.y,
                    fmaf(x[i].z,wv.z, fmaf(x[i].w,wv.w, acc[i][j]))));
      }
    }
  }
#pragma unroll
  for (int i = 0; i < 4; i++) {
#pragma unroll
    for (int j = 0; j < 4; j++) {
      XZ[(size_t)(row0 + 4*rg + i) * 256 + col0 + cg + 16*j] = acc[i][j];
    }
  }
}

// ---- fused conv+silu+GEMM2+scan-pass1: 64 rows (4 chunks), 512 threads ----
// LDS 63 KB -> 2 blocks/CU = 16 waves/CU.
__global__ __launch_bounds__(512) void convdbc_scan1_k(const float* __restrict__ XZ,
    const float* __restrict__ cw, const float* __restrict__ cb,
    const float* __restrict__ W,
    const float* __restrict__ dtw, const float* __restrict__ dtb,
    const float* __restrict__ alog,
    float* __restrict__ XI, float* __restrict__ DBC,
    float* __restrict__ AP, float* __restrict__ HZ)
{
  __shared__ float4 sX[64][33];               // conv+silu out, padded (33.8 KB)
  __shared__ float4 sW[32][40];               // [k4][f] padded 36->40 (20 KB)
  __shared__ __align__(16) float sDBC[64*40]; // [row][36 pad 40]      (10.2 KB)
  int tid = threadIdx.x;
  int row0 = blockIdx.x * 64;
  int l0 = row0 & (L_ - 1);
  int b  = row0 >> 11;                        // /2048
  // phase 1: conv+silu staging (64x32 items, 4 iters of 512)
#pragma unroll
  for (int it = 0; it < 4; it++) {
    int i = tid + it * 512;
    int r = i >> 5, k4 = i & 31;
    int l = l0 + r;
    const float* base = XZ + (size_t)(row0 + r) * 256 + k4 * 4;
    float4 z4 = make_float4(0.f,0.f,0.f,0.f);
    float4 t3 = (l >= 3) ? *(const float4*)(base - 3*256) : z4;
    float4 t2 = (l >= 2) ? *(const float4*)(base - 2*256) : z4;
    float4 t1 = (l >= 1) ? *(const float4*)(base - 1*256) : z4;
    float4 t0 = *(const float4*)(base);
    float4 w0 = *(const float4*)(cw + (k4*4+0)*4);
    float4 w1 = *(const float4*)(cw + (k4*4+1)*4);
    float4 w2 = *(const float4*)(cw + (k4*4+2)*4);
    float4 w3 = *(const float4*)(cw + (k4*4+3)*4);
    float4 bb = *(const float4*)(cb + k4*4);
    float4 o;
    o.x = fmaf(t3.x,w0.x, fmaf(t2.x,w0.y, fmaf(t1.x,w0.z, fmaf(t0.x,w0.w, bb.x))));
    o.y = fmaf(t3.y,w1.x, fmaf(t2.y,w1.y, fmaf(t1.y,w1.z, fmaf(t0.y,w1.w, bb.y))));
    o.z = fmaf(t3.z,w2.x, fmaf(t2.z,w2.y, fmaf(t1.z,w2.z, fmaf(t0.z,w2.w, bb.z))));
    o.w = fmaf(t3.w,w3.x, fmaf(t2.w,w3.y, fmaf(t1.w,w3.z, fmaf(t0.w,w3.w, bb.w))));
    o.x = o.x / (1.f + __expf(-o.x));
    o.y = o.y / (1.f + __expf(-o.y));
    o.z = o.z / (1.f + __expf(-o.z));
    o.w = o.w / (1.f + __expf(-o.w));
    sX[r][k4] = o;
    *(float4*)(XI + (size_t)(row0 + r) * 128 + k4 * 4) = o;
  }
  for (int i = tid; i < 36 * 32; i += 512) {
    int f = i >> 5, k4 = i & 31;
    sW[k4][f] = *(const float4*)(W + (size_t)f * 128 + k4 * 4);
  }
  __syncthreads();
  // phase 2: dbc = xi @ xpw^T. 1 row/thread (r=tid>>3 in 0..63), 5 cols
  {
    int r  = tid >> 3;
    int cg = tid & 7;
    float acc[5];
#pragma unroll
    for (int j = 0; j < 5; j++) acc[j] = 0.f;
    for (int k4 = 0; k4 < 32; k4++) {
      float4 x0 = sX[r][k4];
#pragma unroll
      for (int j = 0; j < 5; j++) {
        float4 wv = sW[k4][cg + 8*j];
        acc[j] = fmaf(x0.x,wv.x, fmaf(x0.y,wv.y, fmaf(x0.z,wv.z, fmaf(x0.w,wv.w, acc[j]))));
      }
    }
#pragma unroll
    for (int j = 0; j < 5; j++) {
      int c = cg + 8*j;
      if (c < 36) {
        DBC[(size_t)(row0 + r) * 36 + c] = acc[j];
        sDBC[r*40 + c] = acc[j];
      }
    }
  }
  __syncthreads();
  // phase 3: chunk-scan summaries. 128 e-lanes x 4 quarters; quarter scans its chunk.
  {
    int e = tid & 127;
    int q = tid >> 7;                           // 0..3
    float a[NS];
#pragma unroll
    for (int n = 0; n < NS; n++) a[n] = -__expf(alog[e*NS + n]);
    // fast path: a[n] == -(n+1) (A_log = log(1..N)) -> da[n] = r^{n+1}, r=exp(-delta)
    bool fast = true;
#pragma unroll
    for (int n = 0; n < NS; n++) fast = fast && (fabsf(a[n] + (float)(n+1)) <= 1e-3f);
    float4 w4 = *(const float4*)(dtw + e*4);
    float bias = dtb[e];
    const float* sXf = (const float*)sX;
    float h[NS];
#pragma unroll
    for (int n = 0; n < NS; n++) h[n] = 0.f;
    float Ssum = 0.f;
    for (int t = 0; t < CHLEN; t++) {
      int r = q * CHLEN + t;
      const float* dr = sDBC + r * 40;
      float4 d4 = *(const float4*)dr;
      float pre = fmaf(d4.x,w4.x, fmaf(d4.y,w4.y, fmaf(d4.z,w4.z, fmaf(d4.w,w4.w, bias))));
      float ex = __expf(pre);
      float delta = (pre > 20.f) ? pre : __logf(1.f + ex);   // softplus
      Ssum += delta;
      float xi = sXf[r * 132 + e];
      float dx = delta * xi;
      float4 b0 = *(const float4*)(dr + 4);
      float4 b1 = *(const float4*)(dr + 8);
      float4 b2 = *(const float4*)(dr + 12);
      float4 b3 = *(const float4*)(dr + 16);
      float Bv[NS] = {b0.x,b0.y,b0.z,b0.w, b1.x,b1.y,b1.z,b1.w,
                      b2.x,b2.y,b2.z,b2.w, b3.x,b3.y,b3.z,b3.w};
      float p[NS];
      if (fast) {
        pow_chain16(__expf(-delta), p);
      } else {
#pragma unroll
        for (int n = 0; n < NS; n++) p[n] = __expf(delta * a[n]);
      }
#pragma unroll
      for (int n = 0; n < NS; n++) h[n] = fmaf(p[n], h[n], dx * Bv[n]);
    }
    float ap[NS];
    if (fast) {
      pow_chain16(__expf(-Ssum), ap);
    } else {
#pragma unroll
      for (int n = 0; n < NS; n++) ap[n] = __expf(a[n] * Ssum);
    }
    int ch = (l0 >> 4) + q;
    size_t base = (size_t)ch * SEQS + ((size_t)(b * ED_ + e)) * NS;
#pragma unroll
    for (int i = 0; i < 4; i++) {
      *(float4*)(AP + base + i*4) = make_float4(ap[4*i], ap[4*i+1], ap[4*i+2], ap[4*i+3]);
      *(float4*)(HZ + base + i*4) = make_float4(h[4*i],  h[4*i+1],  h[4*i+2],  h[4*i+3]);
    }
  }
}

// ---- scan combine: wave-parallel scan over 128 chunk summaries per sequence ----
__global__ __launch_bounds__(256) void scan_combine_k(const float* __restrict__ AP,
    const float* __restrict__ HZ, float* __restrict__ HI)
{
  __shared__ float sA[CHUNKS * 33];
  __shared__ float sH[CHUNKS * 33];
  int tid = threadIdx.x;
  int t0 = blockIdx.x * 32;
  for (int i = tid; i < CHUNKS * 32; i += 256) {
    int ch = i >> 5, s = i & 31;
    sA[ch*33 + s] = AP[(size_t)ch * SEQS + t0 + s];
    sH[ch*33 + s] = HZ[(size_t)ch * SEQS + t0 + s];
  }
  __syncthreads();
  int lane = tid & 63;
  int wid = tid >> 6;
  for (int j = 0; j < 8; j++) {
    int s = wid * 8 + j;
    float a0 = sA[(2*lane)*33 + s],   h0 = sH[(2*lane)*33 + s];
    float a1 = sA[(2*lane+1)*33 + s], h1 = sH[(2*lane+1)*33 + s];
    float aL = a0 * a1;
    float hL = fmaf(a1, h0, h1);
#pragma unroll
    for (int off = 1; off < 64; off <<= 1) {
      float aP = __shfl_up(aL, off, 64);
      float hP = __shfl_up(hL, off, 64);
      if (lane >= off) { hL = fmaf(aL, hP, hL); aL = aP * aL; }
    }
    float hPrev = __shfl_up(hL, 1, 64);
    if (lane == 0) hPrev = 0.f;
    sA[(2*lane)*33 + s]   = hPrev;
    sA[(2*lane+1)*33 + s] = fmaf(a0, hPrev, h0);
  }
  __syncthreads();
  for (int i = tid; i < CHUNKS * 32; i += 256) {
    int ch = i >> 5, s = i & 31;
    HI[(size_t)ch * SEQS + t0 + s] = sA[ch*33 + s];
  }
}

// ---- pass2 + gating + out-proj + residual. 512 thr, 4 chunks (64 rows)/block ----
__global__ __launch_bounds__(512) void pass2_out_k(
    const float* __restrict__ DBC_, const float* __restrict__ XI_,
    const float* __restrict__ XZ,
    const float* __restrict__ dtw, const float* __restrict__ dtb,
    const float* __restrict__ alog, const float* __restrict__ Dp_,
    const float* __restrict__ HI,
    const float* __restrict__ Wo, const float* __restrict__ XOLD,
    float* __restrict__ XNEW)
{
  __shared__ __align__(16) float sYX[64 * 132];  // staged XI -> gated y (33.8 KB)
  __shared__ float4 sWo[64][33];                 // [o][k4] padded      (33.8 KB)
  __shared__ __align__(16) float sDBC[64*40];    // [row][36 pad 40]    (10.2 KB)
  int tid = threadIdx.x;
  int row0 = blockIdx.x * 64;                    // 64 rows, within one batch
  int b   = row0 >> 11;
  int ch0 = (row0 & (L_ - 1)) >> 4;              // first of 4 chunks
#pragma unroll
  for (int it = 0; it < 4; it++) {
    int i = tid + it * 512;
    int o = i >> 5, k4 = i & 31;
    sWo[o][k4] = *(const float4*)(Wo + (size_t)o * 128 + k4 * 4);
  }
#pragma unroll
  for (int it = 0; it < 16; it++) {
    int i = tid + it * 512;
    int r = i >> 7, e = i & 127;
    sYX[r * 132 + e] = XI_[(size_t)row0 * 128 + i];
  }
  for (int i = tid; i < 64 * 36; i += 512) {
    sDBC[(i / 36) * 40 + (i % 36)] = DBC_[(size_t)row0 * 36 + i];
  }
  __syncthreads();
  // scan phase: 128 e-lanes x 4 chunk-quarters
  {
    int e  = tid & 127;
    int q  = tid >> 7;                           // 0..3
    int ch = ch0 + q;
    float a[NS];
#pragma unroll
    for (int n = 0; n < NS; n++) a[n] = -__expf(alog[e*NS + n]);
    bool fast = true;
#pragma unroll
    for (int n = 0; n < NS; n++) fast = fast && (fabsf(a[n] + (float)(n+1)) <= 1e-3f);
    float4 w4 = *(const float4*)(dtw + e*4);
    float bias = dtb[e];
    float Dp = Dp_[e];
    size_t sbase = (size_t)ch * SEQS + ((size_t)(b * ED_ + e)) * NS;
    float h[NS];
#pragma unroll
    for (int i = 0; i < 4; i++) {
      float4 v = *(const float4*)(HI + sbase + i*4);
      h[4*i] = v.x; h[4*i+1] = v.y; h[4*i+2] = v.z; h[4*i+3] = v.w;
    }
    for (int t = 0; t < CHLEN; t++) {
      int r = q * CHLEN + t;
      int bl = b * L_ + ch * CHLEN + t;
      const float* dr = sDBC + r * 40;
      float4 d4 = *(const float4*)dr;
      float pre = fmaf(d4.x,w4.x, fmaf(d4.y,w4.y, fmaf(d4.z,w4.z, fmaf(d4.w,w4.w, bias))));
      float ex = __expf(pre);
      float delta = (pre > 20.f) ? pre : __logf(1.f + ex);
      float xi = sYX[r * 132 + e];
      float dx = delta * xi;
      float4 b0 = *(const float4*)(dr + 4);
      float4 b1 = *(const float4*)(dr + 8);
      float4 b2 = *(const float4*)(dr + 12);
      float4 b3 = *(const float4*)(dr + 16);
      float4 c0 = *(const float4*)(dr + 20);
      float4 c1 = *(const float4*)(dr + 24);
      float4 c2 = *(const float4*)(dr + 28);
      float4 c3 = *(const float4*)(dr + 32);
      float Bv[NS] = {b0.x,b0.y,b0.z,b0.w, b1.x,b1.y,b1.z,b1.w,
                      b2.x,b2.y,b2.z,b2.w, b3.x,b3.y,b3.z,b3.w};
      float Cv[NS] = {c0.x,c0.y,c0.z,c0.w, c1.x,c1.y,c1.z,c1.w,
                      c2.x,c2.y,c2.z,c2.w, c3.x,c3.y,c3.z,c3.w};
      float p[NS];
      if (fast) {
        pow_chain16(__expf(-delta), p);
      } else {
#pragma unroll
        for (int n = 0; n < NS; n++) p[n] = __expf(delta * a[n]);
      }
      float y = 0.f;
#pragma unroll
      for (int n = 0; n < NS; n++) {
        h[n] = fmaf(p[n], h[n], dx * Bv[n]);
        y = fmaf(h[n], Cv[n], y);
      }
      y = fmaf(Dp, xi, y);
      float z = XZ[(size_t)bl * 256 + 128 + e];
      float sz = z / (1.f + __expf(-z));
      sYX[r * 132 + e] = y * sz;      // overwrite xi slot with gated y
    }
  }
  __syncthreads();
  // out-proj from LDS: 2 rows x 4 cols per thread (r2 = tid>>4, og = tid&15)
  {
    int r2 = tid >> 4;                 // 0..31 -> rows 2r2, 2r2+1
    int og = tid & 15;                 // cols og + 16j, j<4
    const float4* sY0 = (const float4*)(sYX + (2*r2    ) * 132);
    const float4* sY1 = (const float4*)(sYX + (2*r2 + 1) * 132);
    float acc0[4], acc1[4];
#pragma unroll
    for (int j = 0; j < 4; j++) { acc0[j] = 0.f; acc1[j] = 0.f; }
    for (int k4 = 0; k4 < 32; k4++) {
      float4 y0 = sY0[k4];
      float4 y1 = sY1[k4];
#pragma unroll
      for (int j = 0; j < 4; j++) {
        float4 wv = sWo[og + 16*j][k4];
        acc0[j] = fmaf(y0.x,wv.x, fmaf(y0.y,wv.y, fmaf(y0.z,wv.z, fmaf(y0.w,wv.w, acc0[j]))));
        acc1[j] = fmaf(y1.x,wv.x, fmaf(y1.y,wv.y, fmaf(y1.z,wv.z, fmaf(y1.w,wv.w, acc1[j]))));
      }
    }
#pragma unroll
    for (int j = 0; j < 4; j++) {
      int o = og + 16*j;
      size_t i0 = (size_t)(row0 + 2*r2    ) * 64 + o;
      size_t i1 = (size_t)(row0 + 2*r2 + 1) * 64 + o;
      XNEW[i0] = XOLD[i0] + acc0[j];
      XNEW[i1] = XOLD[i1] + acc1[j];
    }
  }
}

// ---- final head ----
__global__ __launch_bounds__(256) void final_k(const float* __restrict__ X,
    const float* __restrict__ fcw, const float* __restrict__ fcb, float* __restrict__ out)
{
  int t = blockIdx.x * 256 + threadIdx.x;   // 1024
  int b = t >> 6, o = t & 63;
  const float* xrow = X + ((size_t)b * L_ + (L_ - 1)) * 64;
  const float* wrow = fcw + o * 64;
  float acc = fcb[o];
#pragma unroll
  for (int d = 0; d < 64; d++) acc = fmaf(xrow[d], wrow[d], acc);
  out[t] = acc;
}

extern "C" void kernel_launch(void* const* d_in, const int* in_sizes, int n_in,
                              void* d_out, int out_size, void* d_ws, size_t ws_size,
                              hipStream_t stream)
{
  const float* x_in   = (const float*)d_in[0];
  const float* norm_w = (const float*)d_in[1];
  const float* in_w   = (const float*)d_in[2];
  const float* conv_w = (const float*)d_in[3];
  const float* conv_b = (const float*)d_in[4];
  const float* xp_w   = (const float*)d_in[5];
  const float* dt_w   = (const float*)d_in[6];
  const float* dt_b   = (const float*)d_in[7];
  const float* A_log  = (const float*)d_in[8];
  const float* D_skip = (const float*)d_in[9];
  const float* out_w  = (const float*)d_in[10];
  const float* fc_w   = (const float*)d_in[11];
  const float* fc_b   = (const float*)d_in[12];
  float* out = (float*)d_out;

  float* ws  = (float*)d_ws;
  float* X   = ws;                                  // BL*64
  float* XZ  = X   + (size_t)BL*64;                 // BL*256
  float* XI  = XZ  + (size_t)BL*256;                // BL*128
  float* DBC = XI  + (size_t)BL*128;                // BL*36
  float* AP  = DBC + (size_t)BL*36;                 // CHUNKS*SEQS
  float* HZ  = AP  + (size_t)CHUNKS*SEQS;
  float* HI  = HZ  + (size_t)CHUNKS*SEQS;

  for (int l = 0; l < NL_; l++) {
    const float* xsrc = (l == 0) ? x_in : X;
    gemm_in_rms_k<<<dim3(BL/64, 4), 256, 0, stream>>>(xsrc, norm_w + l*DM,
                    in_w + (size_t)l*2*ED_*DM, XZ);
    convdbc_scan1_k<<<BL/64, 512, 0, stream>>>(XZ, conv_w + l*ED_*4, conv_b + l*ED_,
                    xp_w + (size_t)l*36*ED_,
                    dt_w + l*ED_*RK, dt_b + l*ED_, A_log + l*ED_*NS,
                    XI, DBC, AP, HZ);
    scan_combine_k<<<SEQS/32, 256, 0, stream>>>(AP, HZ, HI);
    pass2_out_k<<<BL/64, 512, 0, stream>>>(DBC, XI, XZ,
                    dt_w + l*ED_*RK, dt_b + l*ED_, A_log + l*ED_*NS, D_skip + l*ED_,
                    HI, out_w + (size_t)l*DM*ED_, xsrc, X);
  }
  final_k<<<4, 256, 0, stream>>>(X, fc_w, fc_b, out);
}

// Round 20
// 388.809 us; speedup vs baseline: 1.0250x; 1.0109x over previous
//
#include <hip/hip_runtime.h>
#include <math.h>

// MambaForecaster: B=16, L=2048, Dm=64, NL=4, ED=128, N=16, R=4, DC=4
#define B_   16
#define L_   2048
#define DM   64
#define NL_  4
#define ED_  128
#define NS   16
#define RK   4
#define BL   (B_*L_)          // 32768 rows
#define CHUNKS 128
#define CHLEN  (L_/CHUNKS)    // 16
#define SEQS   (B_*ED_*NS)    // 32768 sequences for the combine

// Build r^{1..16} from r with 15 muls (depth 4). p[n] = r^{n+1}.
__device__ __forceinline__ void pow_chain16(float r, float* p) {
  float r2 = r * r, r4 = r2 * r2, r8 = r4 * r4;
  p[0]=r;      p[1]=r2;      p[2]=r2*r;    p[3]=r4;
  p[4]=r4*r;   p[5]=r4*r2;   p[6]=r4*p[2]; p[7]=r8;
  p[8]=r8*r;   p[9]=r8*r2;   p[10]=r8*p[2];p[11]=r8*r4;
  p[12]=r8*p[4];p[13]=r8*p[5];p[14]=r8*p[6];p[15]=r8*r8;
}

// ---- GEMM1 + fused RMSNorm (layer 0 only): xz = rmsnorm(x) @ in_w^T ----
__global__ __launch_bounds__(256) void gemm_in_rms_k(const float* __restrict__ X,
    const float* __restrict__ nw, const float* __restrict__ W, float* __restrict__ XZ)
{
  __shared__ float4 sX[64][17];    // 64 rows x 64 K, padded (17.4 KB)
  __shared__ float4 sW[16][64];    // [k4][c], 64 cols       (16 KB)
  int tid = threadIdx.x;
  int row0 = blockIdx.x * 64;
  int col0 = blockIdx.y * 64;
  const float* Wh = W + (size_t)col0 * 64;
#pragma unroll
  for (int it = 0; it < 4; it++) {
    int i = tid + it * 256;
    int r = i >> 4, q = i & 15;
    float4 v = *(const float4*)(X + (size_t)(row0 + r) * 64 + q * 4);
    float ss = v.x*v.x + v.y*v.y + v.z*v.z + v.w*v.w;
    ss += __shfl_xor(ss, 1, 16);
    ss += __shfl_xor(ss, 2, 16);
    ss += __shfl_xor(ss, 4, 16);
    ss += __shfl_xor(ss, 8, 16);
    float sc = rsqrtf(ss * (1.0f/64.0f) + 1e-5f);
    float4 wv = *(const float4*)(nw + q * 4);
    float4 o;
    o.x = v.x*sc*wv.x; o.y = v.y*sc*wv.y; o.z = v.z*sc*wv.z; o.w = v.w*sc*wv.w;
    sX[r][q] = o;
  }
#pragma unroll
  for (int it = 0; it < 4; it++) {
    int i = tid + it * 256;
    int c = i >> 4, k4 = i & 15;
    sW[k4][c] = *(const float4*)(Wh + (size_t)c * 64 + k4 * 4);
  }
  __syncthreads();
  int rg = tid >> 4;
  int cg = tid & 15;
  float acc[4][4];
#pragma unroll
  for (int i = 0; i < 4; i++)
#pragma unroll
    for (int j = 0; j < 4; j++) acc[i][j] = 0.f;
  for (int k4 = 0; k4 < 16; k4++) {
    float4 x[4];
#pragma unroll
    for (int i = 0; i < 4; i++) x[i] = sX[4*rg + i][k4];
#pragma unroll
    for (int j = 0; j < 4; j++) {
      float4 wv = sW[k4][cg + 16*j];
#pragma unroll
      for (int i = 0; i < 4; i++) {
        acc[i][j] = fmaf(x[i].x,wv.x, fmaf(x[i].y,wv.y,
                    fmaf(x[i].z,wv.z, fmaf(x[i].w,wv.w, acc[i][j]))));
      }
    }
  }
#pragma unroll
  for (int i = 0; i < 4; i++) {
#pragma unroll
    for (int j = 0; j < 4; j++) {
      XZ[(size_t)(row0 + 4*rg + i) * 256 + col0 + cg + 16*j] = acc[i][j];
    }
  }
}

// ---- fused conv+silu+GEMM2+scan-pass1: 64 rows (4 chunks), 512 threads ----
__global__ __launch_bounds__(512) void convdbc_scan1_k(const float* __restrict__ XZ,
    const float* __restrict__ cw, const float* __restrict__ cb,
    const float* __restrict__ W,
    const float* __restrict__ dtw, const float* __restrict__ dtb,
    const float* __restrict__ alog,
    float* __restrict__ XI, float* __restrict__ DBC,
    float* __restrict__ AP, float* __restrict__ HZ)
{
  __shared__ float4 sX[64][33];               // conv+silu out, padded (33.8 KB)
  __shared__ float4 sW[32][40];               // [k4][f] padded 36->40 (20 KB)
  __shared__ __align__(16) float sDBC[64*40]; // [row][36 pad 40]      (10.2 KB)
  int tid = threadIdx.x;
  int row0 = blockIdx.x * 64;
  int l0 = row0 & (L_ - 1);
  int b  = row0 >> 11;
#pragma unroll
  for (int it = 0; it < 4; it++) {
    int i = tid + it * 512;
    int r = i >> 5, k4 = i & 31;
    int l = l0 + r;
    const float* base = XZ + (size_t)(row0 + r) * 256 + k4 * 4;
    float4 z4 = make_float4(0.f,0.f,0.f,0.f);
    float4 t3 = (l >= 3) ? *(const float4*)(base - 3*256) : z4;
    float4 t2 = (l >= 2) ? *(const float4*)(base - 2*256) : z4;
    float4 t1 = (l >= 1) ? *(const float4*)(base - 1*256) : z4;
    float4 t0 = *(const float4*)(base);
    float4 w0 = *(const float4*)(cw + (k4*4+0)*4);
    float4 w1 = *(const float4*)(cw + (k4*4+1)*4);
    float4 w2 = *(const float4*)(cw + (k4*4+2)*4);
    float4 w3 = *(const float4*)(cw + (k4*4+3)*4);
    float4 bb = *(const float4*)(cb + k4*4);
    float4 o;
    o.x = fmaf(t3.x,w0.x, fmaf(t2.x,w0.y, fmaf(t1.x,w0.z, fmaf(t0.x,w0.w, bb.x))));
    o.y = fmaf(t3.y,w1.x, fmaf(t2.y,w1.y, fmaf(t1.y,w1.z, fmaf(t0.y,w1.w, bb.y))));
    o.z = fmaf(t3.z,w2.x, fmaf(t2.z,w2.y, fmaf(t1.z,w2.z, fmaf(t0.z,w2.w, bb.z))));
    o.w = fmaf(t3.w,w3.x, fmaf(t2.w,w3.y, fmaf(t1.w,w3.z, fmaf(t0.w,w3.w, bb.w))));
    o.x = o.x / (1.f + __expf(-o.x));
    o.y = o.y / (1.f + __expf(-o.y));
    o.z = o.z / (1.f + __expf(-o.z));
    o.w = o.w / (1.f + __expf(-o.w));
    sX[r][k4] = o;
    *(float4*)(XI + (size_t)(row0 + r) * 128 + k4 * 4) = o;
  }
  for (int i = tid; i < 36 * 32; i += 512) {
    int f = i >> 5, k4 = i & 31;
    sW[k4][f] = *(const float4*)(W + (size_t)f * 128 + k4 * 4);
  }
  __syncthreads();
  {
    int r  = tid >> 3;
    int cg = tid & 7;
    float acc[5];
#pragma unroll
    for (int j = 0; j < 5; j++) acc[j] = 0.f;
    for (int k4 = 0; k4 < 32; k4++) {
      float4 x0 = sX[r][k4];
#pragma unroll
      for (int j = 0; j < 5; j++) {
        float4 wv = sW[k4][cg + 8*j];
        acc[j] = fmaf(x0.x,wv.x, fmaf(x0.y,wv.y, fmaf(x0.z,wv.z, fmaf(x0.w,wv.w, acc[j]))));
      }
    }
#pragma unroll
    for (int j = 0; j < 5; j++) {
      int c = cg + 8*j;
      if (c < 36) {
        DBC[(size_t)(row0 + r) * 36 + c] = acc[j];
        sDBC[r*40 + c] = acc[j];
      }
    }
  }
  __syncthreads();
  {
    int e = tid & 127;
    int q = tid >> 7;
    float a[NS];
#pragma unroll
    for (int n = 0; n < NS; n++) a[n] = -__expf(alog[e*NS + n]);
    bool fast = true;
#pragma unroll
    for (int n = 0; n < NS; n++) fast = fast && (fabsf(a[n] + (float)(n+1)) <= 1e-3f);
    float4 w4 = *(const float4*)(dtw + e*4);
    float bias = dtb[e];
    const float* sXf = (const float*)sX;
    float h[NS];
#pragma unroll
    for (int n = 0; n < NS; n++) h[n] = 0.f;
    float Ssum = 0.f;
    for (int t = 0; t < CHLEN; t++) {
      int r = q * CHLEN + t;
      const float* dr = sDBC + r * 40;
      float4 d4 = *(const float4*)dr;
      float pre = fmaf(d4.x,w4.x, fmaf(d4.y,w4.y, fmaf(d4.z,w4.z, fmaf(d4.w,w4.w, bias))));
      float ex = __expf(pre);
      float delta = (pre > 20.f) ? pre : __logf(1.f + ex);
      Ssum += delta;
      float xi = sXf[r * 132 + e];
      float dx = delta * xi;
      float4 b0 = *(const float4*)(dr + 4);
      float4 b1 = *(const float4*)(dr + 8);
      float4 b2 = *(const float4*)(dr + 12);
      float4 b3 = *(const float4*)(dr + 16);
      float Bv[NS] = {b0.x,b0.y,b0.z,b0.w, b1.x,b1.y,b1.z,b1.w,
                      b2.x,b2.y,b2.z,b2.w, b3.x,b3.y,b3.z,b3.w};
      float p[NS];
      if (fast) {
        pow_chain16(__expf(-delta), p);
      } else {
#pragma unroll
        for (int n = 0; n < NS; n++) p[n] = __expf(delta * a[n]);
      }
#pragma unroll
      for (int n = 0; n < NS; n++) h[n] = fmaf(p[n], h[n], dx * Bv[n]);
    }
    float ap[NS];
    if (fast) {
      pow_chain16(__expf(-Ssum), ap);
    } else {
#pragma unroll
      for (int n = 0; n < NS; n++) ap[n] = __expf(a[n] * Ssum);
    }
    int ch = (l0 >> 4) + q;
    size_t base = (size_t)ch * SEQS + ((size_t)(b * ED_ + e)) * NS;
#pragma unroll
    for (int i = 0; i < 4; i++) {
      *(float4*)(AP + base + i*4) = make_float4(ap[4*i], ap[4*i+1], ap[4*i+2], ap[4*i+3]);
      *(float4*)(HZ + base + i*4) = make_float4(h[4*i],  h[4*i+1],  h[4*i+2],  h[4*i+3]);
    }
  }
}

// ---- scan combine: wave-parallel scan over 128 chunk summaries per sequence ----
__global__ __launch_bounds__(256) void scan_combine_k(const float* __restrict__ AP,
    const float* __restrict__ HZ, float* __restrict__ HI)
{
  __shared__ float sA[CHUNKS * 33];
  __shared__ float sH[CHUNKS * 33];
  int tid = threadIdx.x;
  int t0 = blockIdx.x * 32;
  for (int i = tid; i < CHUNKS * 32; i += 256) {
    int ch = i >> 5, s = i & 31;
    sA[ch*33 + s] = AP[(size_t)ch * SEQS + t0 + s];
    sH[ch*33 + s] = HZ[(size_t)ch * SEQS + t0 + s];
  }
  __syncthreads();
  int lane = tid & 63;
  int wid = tid >> 6;
  for (int j = 0; j < 8; j++) {
    int s = wid * 8 + j;
    float a0 = sA[(2*lane)*33 + s],   h0 = sH[(2*lane)*33 + s];
    float a1 = sA[(2*lane+1)*33 + s], h1 = sH[(2*lane+1)*33 + s];
    float aL = a0 * a1;
    float hL = fmaf(a1, h0, h1);
#pragma unroll
    for (int off = 1; off < 64; off <<= 1) {
      float aP = __shfl_up(aL, off, 64);
      float hP = __shfl_up(hL, off, 64);
      if (lane >= off) { hL = fmaf(aL, hP, hL); aL = aP * aL; }
    }
    float hPrev = __shfl_up(hL, 1, 64);
    if (lane == 0) hPrev = 0.f;
    sA[(2*lane)*33 + s]   = hPrev;
    sA[(2*lane+1)*33 + s] = fmaf(a0, hPrev, h0);
  }
  __syncthreads();
  for (int i = tid; i < CHUNKS * 32; i += 256) {
    int ch = i >> 5, s = i & 31;
    HI[(size_t)ch * SEQS + t0 + s] = sA[ch*33 + s];
  }
}

// ---- pass2 + gating + out-proj + residual + (fused next-layer rmsnorm+in-proj) --
__global__ __launch_bounds__(512) void pass2_out_k(
    const float* __restrict__ DBC_, const float* __restrict__ XI_,
    const float* __restrict__ XZ,
    const float* __restrict__ dtw, const float* __restrict__ dtb,
    const float* __restrict__ alog, const float* __restrict__ Dp_,
    const float* __restrict__ HI,
    const float* __restrict__ Wo, const float* __restrict__ XOLD,
    float* __restrict__ XNEW,
    int doNext, const float* __restrict__ nw_next,
    const float* __restrict__ W_next, float* __restrict__ XZn)
{
  __shared__ __align__(16) float sYX[64 * 132];  // staged XI -> gated y (33.8 KB)
  __shared__ float4 sWo[64][33];                 // [o][k4] padded      (33.8 KB)
  __shared__ __align__(16) float sDBC[64*40];    // [row][36 pad 40]    (10.2 KB)
  int tid = threadIdx.x;
  int row0 = blockIdx.x * 64;                    // 64 rows, within one batch
  int b   = row0 >> 11;
  int ch0 = (row0 & (L_ - 1)) >> 4;              // first of 4 chunks
#pragma unroll
  for (int it = 0; it < 4; it++) {
    int i = tid + it * 512;
    int o = i >> 5, k4 = i & 31;
    sWo[o][k4] = *(const float4*)(Wo + (size_t)o * 128 + k4 * 4);
  }
#pragma unroll
  for (int it = 0; it < 16; it++) {
    int i = tid + it * 512;
    int r = i >> 7, e = i & 127;
    sYX[r * 132 + e] = XI_[(size_t)row0 * 128 + i];
  }
  for (int i = tid; i < 64 * 36; i += 512) {
    sDBC[(i / 36) * 40 + (i % 36)] = DBC_[(size_t)row0 * 36 + i];
  }
  __syncthreads();
  // scan phase: 128 e-lanes x 4 chunk-quarters
  {
    int e  = tid & 127;
    int q  = tid >> 7;
    int ch = ch0 + q;
    float a[NS];
#pragma unroll
    for (int n = 0; n < NS; n++) a[n] = -__expf(alog[e*NS + n]);
    bool fast = true;
#pragma unroll
    for (int n = 0; n < NS; n++) fast = fast && (fabsf(a[n] + (float)(n+1)) <= 1e-3f);
    float4 w4 = *(const float4*)(dtw + e*4);
    float bias = dtb[e];
    float Dp = Dp_[e];
    size_t sbase = (size_t)ch * SEQS + ((size_t)(b * ED_ + e)) * NS;
    float h[NS];
#pragma unroll
    for (int i = 0; i < 4; i++) {
      float4 v = *(const float4*)(HI + sbase + i*4);
      h[4*i] = v.x; h[4*i+1] = v.y; h[4*i+2] = v.z; h[4*i+3] = v.w;
    }
    for (int t = 0; t < CHLEN; t++) {
      int r = q * CHLEN + t;
      int bl = b * L_ + ch * CHLEN + t;
      const float* dr = sDBC + r * 40;
      float4 d4 = *(const float4*)dr;
      float pre = fmaf(d4.x,w4.x, fmaf(d4.y,w4.y, fmaf(d4.z,w4.z, fmaf(d4.w,w4.w, bias))));
      float ex = __expf(pre);
      float delta = (pre > 20.f) ? pre : __logf(1.f + ex);
      float xi = sYX[r * 132 + e];
      float dx = delta * xi;
      float4 b0 = *(const float4*)(dr + 4);
      float4 b1 = *(const float4*)(dr + 8);
      float4 b2 = *(const float4*)(dr + 12);
      float4 b3 = *(const float4*)(dr + 16);
      float4 c0 = *(const float4*)(dr + 20);
      float4 c1 = *(const float4*)(dr + 24);
      float4 c2 = *(const float4*)(dr + 28);
      float4 c3 = *(const float4*)(dr + 32);
      float Bv[NS] = {b0.x,b0.y,b0.z,b0.w, b1.x,b1.y,b1.z,b1.w,
                      b2.x,b2.y,b2.z,b2.w, b3.x,b3.y,b3.z,b3.w};
      float Cv[NS] = {c0.x,c0.y,c0.z,c0.w, c1.x,c1.y,c1.z,c1.w,
                      c2.x,c2.y,c2.z,c2.w, c3.x,c3.y,c3.z,c3.w};
      float p[NS];
      if (fast) {
        pow_chain16(__expf(-delta), p);
      } else {
#pragma unroll
        for (int n = 0; n < NS; n++) p[n] = __expf(delta * a[n]);
      }
      float y = 0.f;
#pragma unroll
      for (int n = 0; n < NS; n++) {
        h[n] = fmaf(p[n], h[n], dx * Bv[n]);
        y = fmaf(h[n], Cv[n], y);
      }
      y = fmaf(Dp, xi, y);
      float z = XZ[(size_t)bl * 256 + 128 + e];
      float sz = z / (1.f + __expf(-z));
      sYX[r * 132 + e] = y * sz;
    }
  }
  __syncthreads();
  // out-proj from LDS: 2 rows x 4 cols per thread (r2 = tid>>4, og = tid&15)
  int r2 = tid >> 4;                 // 0..31 -> rows 2r2, 2r2+1
  int og = tid & 15;                 // cols og + 16j, j<4
  float v0[4], v1[4];
  {
    const float4* sY0 = (const float4*)(sYX + (2*r2    ) * 132);
    const float4* sY1 = (const float4*)(sYX + (2*r2 + 1) * 132);
    float acc0[4], acc1[4];
#pragma unroll
    for (int j = 0; j < 4; j++) { acc0[j] = 0.f; acc1[j] = 0.f; }
    for (int k4 = 0; k4 < 32; k4++) {
      float4 y0 = sY0[k4];
      float4 y1 = sY1[k4];
#pragma unroll
      for (int j = 0; j < 4; j++) {
        float4 wv = sWo[og + 16*j][k4];
        acc0[j] = fmaf(y0.x,wv.x, fmaf(y0.y,wv.y, fmaf(y0.z,wv.z, fmaf(y0.w,wv.w, acc0[j]))));
        acc1[j] = fmaf(y1.x,wv.x, fmaf(y1.y,wv.y, fmaf(y1.z,wv.z, fmaf(y1.w,wv.w, acc1[j]))));
      }
    }
#pragma unroll
    for (int j = 0; j < 4; j++) {
      int o = og + 16*j;
      size_t i0 = (size_t)(row0 + 2*r2    ) * 64 + o;
      size_t i1 = (size_t)(row0 + 2*r2 + 1) * 64 + o;
      v0[j] = XOLD[i0] + acc0[j];
      v1[j] = XOLD[i1] + acc1[j];
      XNEW[i0] = v0[j];
      XNEW[i1] = v1[j];
    }
  }
  // ---- fused next-layer rmsnorm + in-proj (reuses sYX/sWo after barrier) ----
  if (doNext) {
    float ss0 = 0.f, ss1 = 0.f;
#pragma unroll
    for (int j = 0; j < 4; j++) { ss0 += v0[j]*v0[j]; ss1 += v1[j]*v1[j]; }
    ss0 += __shfl_xor(ss0, 1, 16); ss0 += __shfl_xor(ss0, 2, 16);
    ss0 += __shfl_xor(ss0, 4, 16); ss0 += __shfl_xor(ss0, 8, 16);
    ss1 += __shfl_xor(ss1, 1, 16); ss1 += __shfl_xor(ss1, 2, 16);
    ss1 += __shfl_xor(ss1, 4, 16); ss1 += __shfl_xor(ss1, 8, 16);
    float sc0 = rsqrtf(ss0 * (1.0f/64.0f) + 1e-5f);
    float sc1 = rsqrtf(ss1 * (1.0f/64.0f) + 1e-5f);
    __syncthreads();                 // all sYX/sWo reads done -> safe to overlay
    float* sXNf = sYX;               // overlay: [64][68] floats (17.4 KB)
    float4 (*sW16)[128] = (float4(*)[128])sWo;  // overlay: 16x128 f4 (32 KB)
#pragma unroll
    for (int j = 0; j < 4; j++) {
      int c = og + 16*j;
      float nwv = nw_next[c];
      sXNf[(2*r2    )*68 + c] = v0[j]*sc0*nwv;
      sXNf[(2*r2 + 1)*68 + c] = v1[j]*sc1*nwv;
    }
    __syncthreads();
    for (int half = 0; half < 2; half++) {
#pragma unroll
      for (int it = 0; it < 4; it++) {
        int i = tid + it * 512;
        int c = i >> 4, k4 = i & 15;
        sW16[k4][c] = *(const float4*)(W_next + (size_t)(half*128 + c) * 64 + k4 * 4);
      }
      __syncthreads();
      const float4* xr0 = (const float4*)(sXNf + (2*r2    ) * 68);
      const float4* xr1 = (const float4*)(sXNf + (2*r2 + 1) * 68);
      float a0[8], a1[8];
#pragma unroll
      for (int j = 0; j < 8; j++) { a0[j] = 0.f; a1[j] = 0.f; }
      for (int k4 = 0; k4 < 16; k4++) {
        float4 x0 = xr0[k4];
        float4 x1 = xr1[k4];
#pragma unroll
        for (int j = 0; j < 8; j++) {
          float4 wv = sW16[k4][og + 16*j];
          a0[j] = fmaf(x0.x,wv.x, fmaf(x0.y,wv.y, fmaf(x0.z,wv.z, fmaf(x0.w,wv.w, a0[j]))));
          a1[j] = fmaf(x1.x,wv.x, fmaf(x1.y,wv.y, fmaf(x1.z,wv.z, fmaf(x1.w,wv.w, a1[j]))));
        }
      }
#pragma unroll
      for (int j = 0; j < 8; j++) {
        int c = half*128 + og + 16*j;
        XZn[(size_t)(row0 + 2*r2    ) * 256 + c] = a0[j];
        XZn[(size_t)(row0 + 2*r2 + 1) * 256 + c] = a1[j];
      }
      if (half == 0) __syncthreads();
    }
  }
}

// ---- final head ----
__global__ __launch_bounds__(256) void final_k(const float* __restrict__ X,
    const float* __restrict__ fcw, const float* __restrict__ fcb, float* __restrict__ out)
{
  int t = blockIdx.x * 256 + threadIdx.x;   // 1024
  int b = t >> 6, o = t & 63;
  const float* xrow = X + ((size_t)b * L_ + (L_ - 1)) * 64;
  const float* wrow = fcw + o * 64;
  float acc = fcb[o];
#pragma unroll
  for (int d = 0; d < 64; d++) acc = fmaf(xrow[d], wrow[d], acc);
  out[t] = acc;
}

extern "C" void kernel_launch(void* const* d_in, const int* in_sizes, int n_in,
                              void* d_out, int out_size, void* d_ws, size_t ws_size,
                              hipStream_t stream)
{
  const float* x_in   = (const float*)d_in[0];
  const float* norm_w = (const float*)d_in[1];
  const float* in_w   = (const float*)d_in[2];
  const float* conv_w = (const float*)d_in[3];
  const float* conv_b = (const float*)d_in[4];
  const float* xp_w   = (const float*)d_in[5];
  const float* dt_w   = (const float*)d_in[6];
  const float* dt_b   = (const float*)d_in[7];
  const float* A_log  = (const float*)d_in[8];
  const float* D_skip = (const float*)d_in[9];
  const float* out_w  = (const float*)d_in[10];
  const float* fc_w   = (const float*)d_in[11];
  const float* fc_b   = (const float*)d_in[12];
  float* out = (float*)d_out;

  float* ws  = (float*)d_ws;
  float* X   = ws;                                  // BL*64
  float* XZ  = X   + (size_t)BL*64;                 // BL*256
  float* XI  = XZ  + (size_t)BL*256;                // BL*128
  float* DBC = XI  + (size_t)BL*128;                // BL*36
  float* AP  = DBC + (size_t)BL*36;                 // CHUNKS*SEQS
  float* HZ  = AP  + (size_t)CHUNKS*SEQS;
  float* HI  = HZ  + (size_t)CHUNKS*SEQS;

  for (int l = 0; l < NL_; l++) {
    const float* xsrc = (l == 0) ? x_in : X;
    if (l == 0) {
      gemm_in_rms_k<<<dim3(BL/64, 4), 256, 0, stream>>>(x_in, norm_w,
                      in_w, XZ);
    }
    convdbc_scan1_k<<<BL/64, 512, 0, stream>>>(XZ, conv_w + l*ED_*4, conv_b + l*ED_,
                    xp_w + (size_t)l*36*ED_,
                    dt_w + l*ED_*RK, dt_b + l*ED_, A_log + l*ED_*NS,
                    XI, DBC, AP, HZ);
    scan_combine_k<<<SEQS/32, 256, 0, stream>>>(AP, HZ, HI);
    int doNext = (l < NL_ - 1) ? 1 : 0;
    int ln = (l < NL_ - 1) ? (l + 1) : l;
    pass2_out_k<<<BL/64, 512, 0, stream>>>(DBC, XI, XZ,
                    dt_w + l*ED_*RK, dt_b + l*ED_, A_log + l*ED_*NS, D_skip + l*ED_,
                    HI, out_w + (size_t)l*DM*ED_, xsrc, X,
                    doNext, norm_w + ln*DM, in_w + (size_t)ln*2*ED_*DM, XZ);
  }
  final_k<<<4, 256, 0, stream>>>(X, fc_w, fc_b, out);
}

// Round 21
// 383.762 us; speedup vs baseline: 1.0384x; 1.0132x over previous
//
#include <hip/hip_runtime.h>
#include <math.h>

// MambaForecaster: B=16, L=2048, Dm=64, NL=4, ED=128, N=16, R=4, DC=4
#define B_   16
#define L_   2048
#define DM   64
#define NL_  4
#define ED_  128
#define NS   16
#define RK   4
#define BL   (B_*L_)          // 32768 rows
#define CHUNKS 128
#define CHLEN  (L_/CHUNKS)    // 16
#define SEQS   (B_*ED_*NS)    // 32768 sequences for the combine

// Build r^{1..16} from r with 15 muls (depth 4). p[n] = r^{n+1}.
__device__ __forceinline__ void pow_chain16(float r, float* p) {
  float r2 = r * r, r4 = r2 * r2, r8 = r4 * r4;
  p[0]=r;      p[1]=r2;      p[2]=r2*r;    p[3]=r4;
  p[4]=r4*r;   p[5]=r4*r2;   p[6]=r4*p[2]; p[7]=r8;
  p[8]=r8*r;   p[9]=r8*r2;   p[10]=r8*p[2];p[11]=r8*r4;
  p[12]=r8*p[4];p[13]=r8*p[5];p[14]=r8*p[6];p[15]=r8*r8;
}

// ---- GEMM1 + fused RMSNorm (layer 0 only): xz = rmsnorm(x) @ in_w^T ----
__global__ __launch_bounds__(256) void gemm_in_rms_k(const float* __restrict__ X,
    const float* __restrict__ nw, const float* __restrict__ W, float* __restrict__ XZ)
{
  __shared__ float4 sX[64][17];    // 64 rows x 64 K, padded (17.4 KB)
  __shared__ float4 sW[16][64];    // [k4][c], 64 cols       (16 KB)
  int tid = threadIdx.x;
  int row0 = blockIdx.x * 64;
  int col0 = blockIdx.y * 64;
  const float* Wh = W + (size_t)col0 * 64;
#pragma unroll
  for (int it = 0; it < 4; it++) {
    int i = tid + it * 256;
    int r = i >> 4, q = i & 15;
    float4 v = *(const float4*)(X + (size_t)(row0 + r) * 64 + q * 4);
    float ss = v.x*v.x + v.y*v.y + v.z*v.z + v.w*v.w;
    ss += __shfl_xor(ss, 1, 16);
    ss += __shfl_xor(ss, 2, 16);
    ss += __shfl_xor(ss, 4, 16);
    ss += __shfl_xor(ss, 8, 16);
    float sc = rsqrtf(ss * (1.0f/64.0f) + 1e-5f);
    float4 wv = *(const float4*)(nw + q * 4);
    float4 o;
    o.x = v.x*sc*wv.x; o.y = v.y*sc*wv.y; o.z = v.z*sc*wv.z; o.w = v.w*sc*wv.w;
    sX[r][q] = o;
  }
#pragma unroll
  for (int it = 0; it < 4; it++) {
    int i = tid + it * 256;
    int c = i >> 4, k4 = i & 15;
    sW[k4][c] = *(const float4*)(Wh + (size_t)c * 64 + k4 * 4);
  }
  __syncthreads();
  int rg = tid >> 4;
  int cg = tid & 15;
  float acc[4][4];
#pragma unroll
  for (int i = 0; i < 4; i++)
#pragma unroll
    for (int j = 0; j < 4; j++) acc[i][j] = 0.f;
  for (int k4 = 0; k4 < 16; k4++) {
    float4 x[4];
#pragma unroll
    for (int i = 0; i < 4; i++) x[i] = sX[4*rg + i][k4];
#pragma unroll
    for (int j = 0; j < 4; j++) {
      float4 wv = sW[k4][cg + 16*j];
#pragma unroll
      for (int i = 0; i < 4; i++) {
        acc[i][j] = fmaf(x[i].x,wv.x, fmaf(x[i].y,wv.y,
                    fmaf(x[i].z,wv.z, fmaf(x[i].w,wv.w, acc[i][j]))));
      }
    }
  }
#pragma unroll
  for (int i = 0; i < 4; i++) {
#pragma unroll
    for (int j = 0; j < 4; j++) {
      XZ[(size_t)(row0 + 4*rg + i) * 256 + col0 + cg + 16*j] = acc[i][j];
    }
  }
}

// ---- fused conv+silu+GEMM2+scan-pass1: 64 rows (4 chunks), 512 threads ----
__global__ __launch_bounds__(512) void convdbc_scan1_k(const float* __restrict__ XZ,
    const float* __restrict__ cw, const float* __restrict__ cb,
    const float* __restrict__ W,
    const float* __restrict__ dtw, const float* __restrict__ dtb,
    const float* __restrict__ alog,
    float* __restrict__ XI, float* __restrict__ DBC,
    float* __restrict__ AP, float* __restrict__ HZ)
{
  __shared__ float4 sX[64][33];               // conv+silu out, padded (33.8 KB)
  __shared__ float4 sW[32][40];               // [k4][f] padded 36->40 (20 KB)
  __shared__ __align__(16) float sDBC[64*40]; // [row][36 pad 40]      (10.2 KB)
  int tid = threadIdx.x;
  int row0 = blockIdx.x * 64;
  int l0 = row0 & (L_ - 1);
  int b  = row0 >> 11;
#pragma unroll
  for (int it = 0; it < 4; it++) {
    int i = tid + it * 512;
    int r = i >> 5, k4 = i & 31;
    int l = l0 + r;
    const float* base = XZ + (size_t)(row0 + r) * 256 + k4 * 4;
    float4 z4 = make_float4(0.f,0.f,0.f,0.f);
    float4 t3 = (l >= 3) ? *(const float4*)(base - 3*256) : z4;
    float4 t2 = (l >= 2) ? *(const float4*)(base - 2*256) : z4;
    float4 t1 = (l >= 1) ? *(const float4*)(base - 1*256) : z4;
    float4 t0 = *(const float4*)(base);
    float4 w0 = *(const float4*)(cw + (k4*4+0)*4);
    float4 w1 = *(const float4*)(cw + (k4*4+1)*4);
    float4 w2 = *(const float4*)(cw + (k4*4+2)*4);
    float4 w3 = *(const float4*)(cw + (k4*4+3)*4);
    float4 bb = *(const float4*)(cb + k4*4);
    float4 o;
    o.x = fmaf(t3.x,w0.x, fmaf(t2.x,w0.y, fmaf(t1.x,w0.z, fmaf(t0.x,w0.w, bb.x))));
    o.y = fmaf(t3.y,w1.x, fmaf(t2.y,w1.y, fmaf(t1.y,w1.z, fmaf(t0.y,w1.w, bb.y))));
    o.z = fmaf(t3.z,w2.x, fmaf(t2.z,w2.y, fmaf(t1.z,w2.z, fmaf(t0.z,w2.w, bb.z))));
    o.w = fmaf(t3.w,w3.x, fmaf(t2.w,w3.y, fmaf(t1.w,w3.z, fmaf(t0.w,w3.w, bb.w))));
    o.x = o.x / (1.f + __expf(-o.x));
    o.y = o.y / (1.f + __expf(-o.y));
    o.z = o.z / (1.f + __expf(-o.z));
    o.w = o.w / (1.f + __expf(-o.w));
    sX[r][k4] = o;
    *(float4*)(XI + (size_t)(row0 + r) * 128 + k4 * 4) = o;
  }
  for (int i = tid; i < 36 * 32; i += 512) {
    int f = i >> 5, k4 = i & 31;
    sW[k4][f] = *(const float4*)(W + (size_t)f * 128 + k4 * 4);
  }
  __syncthreads();
  {
    int r  = tid >> 3;
    int cg = tid & 7;
    float acc[5];
#pragma unroll
    for (int j = 0; j < 5; j++) acc[j] = 0.f;
    for (int k4 = 0; k4 < 32; k4++) {
      float4 x0 = sX[r][k4];
#pragma unroll
      for (int j = 0; j < 5; j++) {
        float4 wv = sW[k4][cg + 8*j];
        acc[j] = fmaf(x0.x,wv.x, fmaf(x0.y,wv.y, fmaf(x0.z,wv.z, fmaf(x0.w,wv.w, acc[j]))));
      }
    }
#pragma unroll
    for (int j = 0; j < 5; j++) {
      int c = cg + 8*j;
      if (c < 36) {
        DBC[(size_t)(row0 + r) * 36 + c] = acc[j];
        sDBC[r*40 + c] = acc[j];
      }
    }
  }
  __syncthreads();
  {
    int e = tid & 127;
    int q = tid >> 7;
    float a[NS];
#pragma unroll
    for (int n = 0; n < NS; n++) a[n] = -__expf(alog[e*NS + n]);
    bool fast = true;
#pragma unroll
    for (int n = 0; n < NS; n++) fast = fast && (fabsf(a[n] + (float)(n+1)) <= 1e-3f);
    float4 w4 = *(const float4*)(dtw + e*4);
    float bias = dtb[e];
    const float* sXf = (const float*)sX;
    float h[NS];
#pragma unroll
    for (int n = 0; n < NS; n++) h[n] = 0.f;
    float Ssum = 0.f;
    for (int t = 0; t < CHLEN; t++) {
      int r = q * CHLEN + t;
      const float* dr = sDBC + r * 40;
      float4 d4 = *(const float4*)dr;
      float pre = fmaf(d4.x,w4.x, fmaf(d4.y,w4.y, fmaf(d4.z,w4.z, fmaf(d4.w,w4.w, bias))));
      float ex = __expf(pre);
      float delta = (pre > 20.f) ? pre : __logf(1.f + ex);
      Ssum += delta;
      float xi = sXf[r * 132 + e];
      float dx = delta * xi;
      float4 b0 = *(const float4*)(dr + 4);
      float4 b1 = *(const float4*)(dr + 8);
      float4 b2 = *(const float4*)(dr + 12);
      float4 b3 = *(const float4*)(dr + 16);
      float Bv[NS] = {b0.x,b0.y,b0.z,b0.w, b1.x,b1.y,b1.z,b1.w,
                      b2.x,b2.y,b2.z,b2.w, b3.x,b3.y,b3.z,b3.w};
      float p[NS];
      if (fast) {
        pow_chain16(__expf(-delta), p);
      } else {
#pragma unroll
        for (int n = 0; n < NS; n++) p[n] = __expf(delta * a[n]);
      }
#pragma unroll
      for (int n = 0; n < NS; n++) h[n] = fmaf(p[n], h[n], dx * Bv[n]);
    }
    float ap[NS];
    if (fast) {
      pow_chain16(__expf(-Ssum), ap);
    } else {
#pragma unroll
      for (int n = 0; n < NS; n++) ap[n] = __expf(a[n] * Ssum);
    }
    int ch = (l0 >> 4) + q;
    size_t base = (size_t)ch * SEQS + ((size_t)(b * ED_ + e)) * NS;
#pragma unroll
    for (int i = 0; i < 4; i++) {
      *(float4*)(AP + base + i*4) = make_float4(ap[4*i], ap[4*i+1], ap[4*i+2], ap[4*i+3]);
      *(float4*)(HZ + base + i*4) = make_float4(h[4*i],  h[4*i+1],  h[4*i+2],  h[4*i+3]);
    }
  }
}

// ---- scan combine: wave-parallel scan over 128 chunk summaries per sequence ----
__global__ __launch_bounds__(256) void scan_combine_k(const float* __restrict__ AP,
    const float* __restrict__ HZ, float* __restrict__ HI)
{
  __shared__ float sA[CHUNKS * 33];
  __shared__ float sH[CHUNKS * 33];
  int tid = threadIdx.x;
  int t0 = blockIdx.x * 32;
  for (int i = tid; i < CHUNKS * 32; i += 256) {
    int ch = i >> 5, s = i & 31;
    sA[ch*33 + s] = AP[(size_t)ch * SEQS + t0 + s];
    sH[ch*33 + s] = HZ[(size_t)ch * SEQS + t0 + s];
  }
  __syncthreads();
  int lane = tid & 63;
  int wid = tid >> 6;
  for (int j = 0; j < 8; j++) {
    int s = wid * 8 + j;
    float a0 = sA[(2*lane)*33 + s],   h0 = sH[(2*lane)*33 + s];
    float a1 = sA[(2*lane+1)*33 + s], h1 = sH[(2*lane+1)*33 + s];
    float aL = a0 * a1;
    float hL = fmaf(a1, h0, h1);
#pragma unroll
    for (int off = 1; off < 64; off <<= 1) {
      float aP = __shfl_up(aL, off, 64);
      float hP = __shfl_up(hL, off, 64);
      if (lane >= off) { hL = fmaf(aL, hP, hL); aL = aP * aL; }
    }
    float hPrev = __shfl_up(hL, 1, 64);
    if (lane == 0) hPrev = 0.f;
    sA[(2*lane)*33 + s]   = hPrev;
    sA[(2*lane+1)*33 + s] = fmaf(a0, hPrev, h0);
  }
  __syncthreads();
  for (int i = tid; i < CHUNKS * 32; i += 256) {
    int ch = i >> 5, s = i & 31;
    HI[(size_t)ch * SEQS + t0 + s] = sA[ch*33 + s];
  }
}

// ---- pass2 + gating + out-proj + residual + (fused next-layer rmsnorm+in-proj) --
__global__ __launch_bounds__(512) void pass2_out_k(
    const float* __restrict__ DBC_, const float* __restrict__ XI_,
    const float* __restrict__ XZ,
    const float* __restrict__ dtw, const float* __restrict__ dtb,
    const float* __restrict__ alog, const float* __restrict__ Dp_,
    const float* __restrict__ HI,
    const float* __restrict__ Wo, const float* __restrict__ XOLD,
    float* __restrict__ XNEW,
    int doNext, const float* __restrict__ nw_next,
    const float* __restrict__ W_next, float* __restrict__ XZn)
{
  __shared__ __align__(16) float sYX[64 * 132];  // staged XI -> gated y (33.8 KB)
  __shared__ float4 sWo[64][33];                 // [o][k4] padded      (33.8 KB)
  __shared__ __align__(16) float sDBC[64*40];    // [row][36 pad 40]    (10.2 KB)
  int tid = threadIdx.x;
  int row0 = blockIdx.x * 64;                    // 64 rows, within one batch
  int b   = row0 >> 11;
  int ch0 = (row0 & (L_ - 1)) >> 4;              // first of 4 chunks
#pragma unroll
  for (int it = 0; it < 4; it++) {
    int i = tid + it * 512;
    int o = i >> 5, k4 = i & 31;
    sWo[o][k4] = *(const float4*)(Wo + (size_t)o * 128 + k4 * 4);
  }
#pragma unroll
  for (int it = 0; it < 16; it++) {
    int i = tid + it * 512;
    int r = i >> 7, e = i & 127;
    sYX[r * 132 + e] = XI_[(size_t)row0 * 128 + i];
  }
  for (int i = tid; i < 64 * 36; i += 512) {
    sDBC[(i / 36) * 40 + (i % 36)] = DBC_[(size_t)row0 * 36 + i];
  }
  __syncthreads();
  // scan phase: 128 e-lanes x 4 chunk-quarters
  {
    int e  = tid & 127;
    int q  = tid >> 7;
    int ch = ch0 + q;
    float a[NS];
#pragma unroll
    for (int n = 0; n < NS; n++) a[n] = -__expf(alog[e*NS + n]);
    bool fast = true;
#pragma unroll
    for (int n = 0; n < NS; n++) fast = fast && (fabsf(a[n] + (float)(n+1)) <= 1e-3f);
    float4 w4 = *(const float4*)(dtw + e*4);
    float bias = dtb[e];
    float Dp = Dp_[e];
    size_t sbase = (size_t)ch * SEQS + ((size_t)(b * ED_ + e)) * NS;
    float h[NS];
#pragma unroll
    for (int i = 0; i < 4; i++) {
      float4 v = *(const float4*)(HI + sbase + i*4);
      h[4*i] = v.x; h[4*i+1] = v.y; h[4*i+2] = v.z; h[4*i+3] = v.w;
    }
    for (int t = 0; t < CHLEN; t++) {
      int r = q * CHLEN + t;
      int bl = b * L_ + ch * CHLEN + t;
      const float* dr = sDBC + r * 40;
      float4 d4 = *(const float4*)dr;
      float pre = fmaf(d4.x,w4.x, fmaf(d4.y,w4.y, fmaf(d4.z,w4.z, fmaf(d4.w,w4.w, bias))));
      float ex = __expf(pre);
      float delta = (pre > 20.f) ? pre : __logf(1.f + ex);
      float xi = sYX[r * 132 + e];
      float dx = delta * xi;
      float4 b0 = *(const float4*)(dr + 4);
      float4 b1 = *(const float4*)(dr + 8);
      float4 b2 = *(const float4*)(dr + 12);
      float4 b3 = *(const float4*)(dr + 16);
      float4 c0 = *(const float4*)(dr + 20);
      float4 c1 = *(const float4*)(dr + 24);
      float4 c2 = *(const float4*)(dr + 28);
      float4 c3 = *(const float4*)(dr + 32);
      float Bv[NS] = {b0.x,b0.y,b0.z,b0.w, b1.x,b1.y,b1.z,b1.w,
                      b2.x,b2.y,b2.z,b2.w, b3.x,b3.y,b3.z,b3.w};
      float Cv[NS] = {c0.x,c0.y,c0.z,c0.w, c1.x,c1.y,c1.z,c1.w,
                      c2.x,c2.y,c2.z,c2.w, c3.x,c3.y,c3.z,c3.w};
      float p[NS];
      if (fast) {
        pow_chain16(__expf(-delta), p);
      } else {
#pragma unroll
        for (int n = 0; n < NS; n++) p[n] = __expf(delta * a[n]);
      }
      float y = 0.f;
#pragma unroll
      for (int n = 0; n < NS; n++) {
        h[n] = fmaf(p[n], h[n], dx * Bv[n]);
        y = fmaf(h[n], Cv[n], y);
      }
      y = fmaf(Dp, xi, y);
      float z = XZ[(size_t)bl * 256 + 128 + e];
      float sz = z / (1.f + __expf(-z));
      sYX[r * 132 + e] = y * sz;
    }
  }
  __syncthreads();
  // out-proj from LDS: 2 rows x 4 cols per thread (r2 = tid>>4, og = tid&15)
  int r2 = tid >> 4;                 // 0..31 -> rows 2r2, 2r2+1
  int og = tid & 15;                 // cols og + 16j, j<4
  float v0[4], v1[4];
  {
    const float4* sY0 = (const float4*)(sYX + (2*r2    ) * 132);
    const float4* sY1 = (const float4*)(sYX + (2*r2 + 1) * 132);
    float acc0[4], acc1[4];
#pragma unroll
    for (int j = 0; j < 4; j++) { acc0[j] = 0.f; acc1[j] = 0.f; }
    for (int k4 = 0; k4 < 32; k4++) {
      float4 y0 = sY0[k4];
      float4 y1 = sY1[k4];
#pragma unroll
      for (int j = 0; j < 4; j++) {
        float4 wv = sWo[og + 16*j][k4];
        acc0[j] = fmaf(y0.x,wv.x, fmaf(y0.y,wv.y, fmaf(y0.z,wv.z, fmaf(y0.w,wv.w, acc0[j]))));
        acc1[j] = fmaf(y1.x,wv.x, fmaf(y1.y,wv.y, fmaf(y1.z,wv.z, fmaf(y1.w,wv.w, acc1[j]))));
      }
    }
#pragma unroll
    for (int j = 0; j < 4; j++) {
      int o = og + 16*j;
      size_t i0 = (size_t)(row0 + 2*r2    ) * 64 + o;
      size_t i1 = (size_t)(row0 + 2*r2 + 1) * 64 + o;
      v0[j] = XOLD[i0] + acc0[j];
      v1[j] = XOLD[i1] + acc1[j];
      XNEW[i0] = v0[j];
      XNEW[i1] = v1[j];
    }
  }
  // ---- fused next-layer rmsnorm + in-proj (reuses sYX/sWo after barrier) ----
  if (doNext) {
    float ss0 = 0.f, ss1 = 0.f;
#pragma unroll
    for (int j = 0; j < 4; j++) { ss0 += v0[j]*v0[j]; ss1 += v1[j]*v1[j]; }
    ss0 += __shfl_xor(ss0, 1, 16); ss0 += __shfl_xor(ss0, 2, 16);
    ss0 += __shfl_xor(ss0, 4, 16); ss0 += __shfl_xor(ss0, 8, 16);
    ss1 += __shfl_xor(ss1, 1, 16); ss1 += __shfl_xor(ss1, 2, 16);
    ss1 += __shfl_xor(ss1, 4, 16); ss1 += __shfl_xor(ss1, 8, 16);
    float sc0 = rsqrtf(ss0 * (1.0f/64.0f) + 1e-5f);
    float sc1 = rsqrtf(ss1 * (1.0f/64.0f) + 1e-5f);
    __syncthreads();                 // all sYX/sWo reads done -> safe to overlay
    float* sXNf = sYX;               // overlay: [64][68] floats (17.4 KB)
    float4 (*sW16)[129] = (float4(*)[129])sWo;  // overlay: 16x129 f4 padded (33.0 KB)
#pragma unroll
    for (int j = 0; j < 4; j++) {
      int c = og + 16*j;
      float nwv = nw_next[c];
      sXNf[(2*r2    )*68 + c] = v0[j]*sc0*nwv;
      sXNf[(2*r2 + 1)*68 + c] = v1[j]*sc1*nwv;
    }
    __syncthreads();
    for (int half = 0; half < 2; half++) {
#pragma unroll
      for (int it = 0; it < 4; it++) {
        int i = tid + it * 512;
        int c = i >> 4, k4 = i & 15;
        sW16[k4][c] = *(const float4*)(W_next + (size_t)(half*128 + c) * 64 + k4 * 4);
      }
      __syncthreads();
      const float4* xr0 = (const float4*)(sXNf + (2*r2    ) * 68);
      const float4* xr1 = (const float4*)(sXNf + (2*r2 + 1) * 68);
      float a0[8], a1[8];
#pragma unroll
      for (int j = 0; j < 8; j++) { a0[j] = 0.f; a1[j] = 0.f; }
      for (int k4 = 0; k4 < 16; k4++) {
        float4 x0 = xr0[k4];
        float4 x1 = xr1[k4];
#pragma unroll
        for (int j = 0; j < 8; j++) {
          float4 wv = sW16[k4][og + 16*j];
          a0[j] = fmaf(x0.x,wv.x, fmaf(x0.y,wv.y, fmaf(x0.z,wv.z, fmaf(x0.w,wv.w, a0[j]))));
          a1[j] = fmaf(x1.x,wv.x, fmaf(x1.y,wv.y, fmaf(x1.z,wv.z, fmaf(x1.w,wv.w, a1[j]))));
        }
      }
#pragma unroll
      for (int j = 0; j < 8; j++) {
        int c = half*128 + og + 16*j;
        XZn[(size_t)(row0 + 2*r2    ) * 256 + c] = a0[j];
        XZn[(size_t)(row0 + 2*r2 + 1) * 256 + c] = a1[j];
      }
      if (half == 0) __syncthreads();
    }
  }
}

// ---- final head ----
__global__ __launch_bounds__(256) void final_k(const float* __restrict__ X,
    const float* __restrict__ fcw, const float* __restrict__ fcb, float* __restrict__ out)
{
  int t = blockIdx.x * 256 + threadIdx.x;   // 1024
  int b = t >> 6, o = t & 63;
  const float* xrow = X + ((size_t)b * L_ + (L_ - 1)) * 64;
  const float* wrow = fcw + o * 64;
  float acc = fcb[o];
#pragma unroll
  for (int d = 0; d < 64; d++) acc = fmaf(xrow[d], wrow[d], acc);
  out[t] = acc;
}

extern "C" void kernel_launch(void* const* d_in, const int* in_sizes, int n_in,
                              void* d_out, int out_size, void* d_ws, size_t ws_size,
                              hipStream_t stream)
{
  const float* x_in   = (const float*)d_in[0];
  const float* norm_w = (const float*)d_in[1];
  const float* in_w   = (const float*)d_in[2];
  const float* conv_w = (const float*)d_in[3];
  const float* conv_b = (const float*)d_in[4];
  const float* xp_w   = (const float*)d_in[5];
  const float* dt_w   = (const float*)d_in[6];
  const float* dt_b   = (const float*)d_in[7];
  const float* A_log  = (const float*)d_in[8];
  const float* D_skip = (const float*)d_in[9];
  const float* out_w  = (const float*)d_in[10];
  const float* fc_w   = (const float*)d_in[11];
  const float* fc_b   = (const float*)d_in[12];
  float* out = (float*)d_out;

  float* ws  = (float*)d_ws;
  float* X   = ws;                                  // BL*64
  float* XZ  = X   + (size_t)BL*64;                 // BL*256
  float* XI  = XZ  + (size_t)BL*256;                // BL*128
  float* DBC = XI  + (size_t)BL*128;                // BL*36
  float* AP  = DBC + (size_t)BL*36;                 // CHUNKS*SEQS
  float* HZ  = AP  + (size_t)CHUNKS*SEQS;
  float* HI  = HZ  + (size_t)CHUNKS*SEQS;

  for (int l = 0; l < NL_; l++) {
    const float* xsrc = (l == 0) ? x_in : X;
    if (l == 0) {
      gemm_in_rms_k<<<dim3(BL/64, 4), 256, 0, stream>>>(x_in, norm_w,
                      in_w, XZ);
    }
    convdbc_scan1_k<<<BL/64, 512, 0, stream>>>(XZ, conv_w + l*ED_*4, conv_b + l*ED_,
                    xp_w + (size_t)l*36*ED_,
                    dt_w + l*ED_*RK, dt_b + l*ED_, A_log + l*ED_*NS,
                    XI, DBC, AP, HZ);
    scan_combine_k<<<SEQS/32, 256, 0, stream>>>(AP, HZ, HI);
    int doNext = (l < NL_ - 1) ? 1 : 0;
    int ln = (l < NL_ - 1) ? (l + 1) : l;
    pass2_out_k<<<BL/64, 512, 0, stream>>>(DBC, XI, XZ,
                    dt_w + l*ED_*RK, dt_b + l*ED_, A_log + l*ED_*NS, D_skip + l*ED_,
                    HI, out_w + (size_t)l*DM*ED_, xsrc, X,
                    doNext, norm_w + ln*DM, in_w + (size_t)ln*2*ED_*DM, XZ);
  }
  final_k<<<4, 256, 0, stream>>>(X, fc_w, fc_b, out);
}